// Round 14
// baseline (304.482 us; speedup 1.0000x reference)
//
#include <hip/hip_runtime.h>
#include <hip/hip_bf16.h>

// ---------------------------------------------------------------------------
// TernaryCIFAR10Net on MI355X — Round 29:
//   fc1+fc2 FUSED (fc1fc2_i8): the split-K parts buffer (16.8 MB write +
//   16.8 MB read) existed only for occupancy. New decomposition: 64 blocks
//   x 512 threads, each block = 16 images (one MFMA M-tile) x all 256
//   channels x full K=4096x2 planes. Per wave NT=2, 16 acc regs, 256 MFMAs
//   (no spill risk). h = relu(alpha*sum/S3 + b) -> LDS hbuf[16][257]
//   (pad kills the fc2 16-way bank conflict), barrier, 160 threads finish
//   fc2 scalar (w2 L1-hot) straight to out. Exact: |256*accH+accL| < 2^28.
//   Eliminates parts traffic + one launch. Everything else = verified R28
//   (259.9 us): split conv1/conv2/conv3 at R22 tiles, stats2-fused signs.
// ---------------------------------------------------------------------------

typedef __attribute__((ext_vector_type(8))) short short8;
typedef __attribute__((ext_vector_type(4))) float f32x4;
typedef __attribute__((ext_vector_type(4))) int i32x4;

#define GLOAD_LDS16(g, l)                                              \
    __builtin_amdgcn_global_load_lds(                                  \
        (const __attribute__((address_space(1))) void*)(g),            \
        (__attribute__((address_space(3))) void*)(l), 16, 0, 0)

__device__ __forceinline__ unsigned short f2bf(float x) {
    unsigned u = __float_as_uint(x);
    return (unsigned short)((u + 0x7fffu + ((u >> 16) & 1u)) >> 16);  // RNE
}
__device__ __forceinline__ float bf2f(unsigned short b) {
    return __uint_as_float(((unsigned)b) << 16);
}

// int side-slots at scr+20: [0]=amaxx [1]=amax1 [2]=amax2
//                           [3]=nnz1 [4]=nnz2 [5]=nnz3
//                           [6]=bmax1 [7]=bmax2 [8]=bmax3  (float bits)
// Scales: identical instruction sequence at every use site (determinism).
__device__ __forceinline__ float calc_S1(const double* __restrict__ scr,
                                         float amaxx) {
    const int* ii = (const int*)(scr + 20);
    const double c2 = scr[2];
    const float alpha1 = (float)(scr[1] / (c2 > 1.0 ? c2 : 1.0));
    const float ub = alpha1 * (float)ii[3] * amaxx + __int_as_float(ii[6]);
    return 32512.0f / fmaxf(ub, 1e-30f);
}
__device__ __forceinline__ float calc_S2(const double* __restrict__ scr,
                                         float amax1) {
    const int* ii = (const int*)(scr + 20);
    const double c2 = scr[6];
    const float alpha2 = (float)(scr[5] / (c2 > 1.0 ? c2 : 1.0));
    const float ub = alpha2 * (float)ii[4] * amax1 + __int_as_float(ii[7]);
    return 32512.0f / fmaxf(ub, 1e-30f);
}
__device__ __forceinline__ float calc_S3(const double* __restrict__ scr,
                                         float amax2) {
    const int* ii = (const int*)(scr + 20);
    const double c2 = scr[10];
    const float alpha3 = (float)(scr[9] / (c2 > 1.0 ? c2 : 1.0));
    const float ub = alpha3 * (float)ii[5] * amax2 + __int_as_float(ii[8]);
    return 32512.0f / fmaxf(ub, 1e-30f);
}

// workspace layout (4-byte units)
#define WS_W1B   0
#define N_W1B    2048                  // 8192 B: [2][64 co][64 k] i8 signs
#define WS_W2P   (WS_W1B + N_W1B)
#define N_W2P    (9*128*64)
#define WS_W3P   (WS_W2P + N_W2P)
#define N_W3P    (9*256*128)
#define WS_WTF1  (WS_W3P + N_W3P)
#define N_WTF1   (256*4096)            // region (i8 signs use 1 MB of it)
#define WS_WTF2  (WS_WTF1 + N_WTF1)
#define N_WTF2   (10*256)
#define WS_A1    (WS_WTF2 + N_WTF2)
#define N_A1     (1024*256*64)         // region: a1q (32MB)
#define WS_A2    (WS_A1 + N_A1)
#define N_A2     (1024*64*128)         // region: a2q (16MB)
#define WS_A3    (WS_A2 + N_A2)
#define N_A3     (1024*16*256)         // region: a3q (8MB)
#define WS_F1    (WS_A3 + N_A3)
#define N_F1     (1024*256)
#define WS_SCR   (WS_F1 + N_F1)

struct TernArgs {
    const float* w[6];
    int n[6];
};

// ---------------------------------------------------------------------------
// Stats pass 1: wi<5 -> sum|w|; wi==5 -> amax(x) -> iscr[0].
// ---------------------------------------------------------------------------
__global__ void tern_stats1(TernArgs ta, double* __restrict__ scr) {
    const int wi = blockIdx.y;
    const float* __restrict__ w = ta.w[wi];
    const int n = ta.n[wi];
    __shared__ double red[4];
    const int lane = threadIdx.x & 63, wv = threadIdx.x >> 6;
    if (wi == 5) {
        float m = 0.f;
        for (int i = blockIdx.x * blockDim.x + threadIdx.x; i < n;
             i += gridDim.x * blockDim.x)
            m = fmaxf(m, fabsf(w[i]));
        #pragma unroll
        for (int off = 32; off > 0; off >>= 1)
            m = fmaxf(m, __shfl_down(m, off, 64));
        if (lane == 0) red[wv] = (double)m;
        __syncthreads();
        if (threadIdx.x == 0) {
            float mm = (float)fmax(fmax(red[0], red[1]), fmax(red[2], red[3]));
            atomicMax((int*)(scr + 20), __float_as_int(mm));
        }
        return;
    }
    double s = 0.0;
    for (int i = blockIdx.x * blockDim.x + threadIdx.x; i < n;
         i += gridDim.x * blockDim.x)
        s += (double)fabsf(w[i]);
    #pragma unroll
    for (int off = 32; off > 0; off >>= 1) s += __shfl_down(s, off, 64);
    if (lane == 0) red[wv] = s;
    __syncthreads();
    if (threadIdx.x == 0)
        atomicAdd(scr + wi * 4, red[0] + red[1] + red[2] + red[3]);
}

// ---------------------------------------------------------------------------
// Stats pass 2 + fused sign writer. wi<5: masked sum/count AND packed sign
// stores in the same element loop; wi==0 additionally zeroes w1b's non-sign
// bytes (disjoint from sign writes -> race-free). wi==5: nnz/bias-max pass.
// ---------------------------------------------------------------------------
__global__ void tern_stats2(TernArgs ta,
                            const float* __restrict__ b1v,
                            const float* __restrict__ b2v,
                            const float* __restrict__ b3v,
                            signed char* __restrict__ w1b,
                            signed char* __restrict__ w2p8,
                            signed char* __restrict__ w3p8,
                            signed char* __restrict__ wtf1b8,
                            signed char* __restrict__ wtf2b8,
                            double* __restrict__ scr) {
    const int wi = blockIdx.y;
    const int lane = threadIdx.x & 63, wv = threadIdx.x >> 6;

    if (wi == 5) {
        int* ii = (int*)(scr + 20);
        const int gw = blockIdx.x * 4 + wv;     // global wave id
        if (gw < 64) {                          // w1 row gw (27 elems)
            const float d = (float)(0.7 * scr[0] / 1728.0);
            const float* row = ta.w[0] + gw * 27;
            int c = (lane < 27) ? (fabsf(row[lane]) > d ? 1 : 0) : 0;
            #pragma unroll
            for (int off = 32; off > 0; off >>= 1)
                c += __shfl_down(c, off, 64);
            if (lane == 0) atomicMax(ii + 3, c);
        } else if (gw < 192) {                  // w2 row gw-64 (576)
            const float d = (float)(0.7 * scr[4] / 73728.0);
            const float* row = ta.w[1] + (long)(gw - 64) * 576;
            int c = 0;
            for (int k = lane; k < 576; k += 64)
                c += (fabsf(row[k]) > d) ? 1 : 0;
            #pragma unroll
            for (int off = 32; off > 0; off >>= 1)
                c += __shfl_down(c, off, 64);
            if (lane == 0) atomicMax(ii + 4, c);
        } else if (gw < 448) {                  // w3 row gw-192 (1152)
            const float d = (float)(0.7 * scr[8] / 294912.0);
            const float* row = ta.w[2] + (long)(gw - 192) * 1152;
            int c = 0;
            for (int k = lane; k < 1152; k += 64)
                c += (fabsf(row[k]) > d) ? 1 : 0;
            #pragma unroll
            for (int off = 32; off > 0; off >>= 1)
                c += __shfl_down(c, off, 64);
            if (lane == 0) atomicMax(ii + 5, c);
        } else if (gw < 451) {                  // biases
            const float* bv = (gw == 448) ? b1v : (gw == 449) ? b2v : b3v;
            const int nb = (gw == 448) ? 64 : (gw == 449) ? 128 : 256;
            float m = 0.f;
            for (int k = lane; k < nb; k += 64) m = fmaxf(m, fabsf(bv[k]));
            #pragma unroll
            for (int off = 32; off > 0; off >>= 1)
                m = fmaxf(m, __shfl_down(m, off, 64));
            if (lane == 0)
                atomicMax(ii + 6 + (gw - 448), __float_as_int(m));
        }
        return;
    }

    const float* __restrict__ w = ta.w[wi];
    const int n = ta.n[wi];
    const float delta = (float)(0.7 * scr[wi * 4] / (double)n);

    if (wi == 0) {
        // zero w1b non-sign bytes (sign slots written by the loop below)
        const int z0 = blockIdx.x * blockDim.x + threadIdx.x;
        const int zstride = gridDim.x * blockDim.x;
        for (int i = z0; i < 8192; i += zstride) {
            const int k = i & 63;
            const int plane = i >> 12;
            const bool sign_slot = plane == 0 ? (k < 27)
                                              : (k >= 32 && k < 59);
            if (!sign_slot) w1b[i] = 0;
        }
    }

    double ms = 0.0, cnt = 0.0;
    for (int i = blockIdx.x * blockDim.x + threadIdx.x; i < n;
         i += gridDim.x * blockDim.x) {
        const float v = w[i];
        const float a = fabsf(v);
        const bool mk = (a > delta);
        if (mk) { ms += (double)a; cnt += 1.0; }
        const signed char s = mk ? (v > 0.0f ? 1 : -1) : 0;
        if (wi == 0) {                       // n = 1728 = 64*27
            const int co = i / 27;
            const int kp = i % 27;           // ci*9 + tap
            w1b[co * 64 + kp] = s;           // BL, k = kp
            w1b[4096 + co * 64 + 32 + kp] = s;   // BH, k = 32+kp
        } else if (wi == 1 || wi == 2) {
            const int CIc = (wi == 1) ? 64 : 128;
            const int COc = (wi == 1) ? 128 : 256;
            signed char* dst = (wi == 1) ? w2p8 : w3p8;
            const int co = i / (CIc * 9);
            const int r = i % (CIc * 9);
            const int ci = r / 9, tap = r % 9;
            dst[(tap * COc + co) * CIc + ci] = s;
        } else if (wi == 3) {                // fc1 signs: k' = px*256 + c
            const int j = i >> 12;
            const int k = i & 4095;
            const int px = k & 15, c = k >> 4;
            wtf1b8[(long)j * 4096 + px * 256 + c] = s;
        } else {                             // wi == 4: fc2 signs
            wtf2b8[i] = s;
        }
    }
    #pragma unroll
    for (int off = 32; off > 0; off >>= 1) {
        ms += __shfl_down(ms, off, 64);
        cnt += __shfl_down(cnt, off, 64);
    }
    __shared__ double redm[4], redc[4];
    if (lane == 0) { redm[wv] = ms; redc[wv] = cnt; }
    __syncthreads();
    if (threadIdx.x == 0) {
        atomicAdd(scr + wi * 4 + 1, redm[0] + redm[1] + redm[2] + redm[3]);
        atomicAdd(scr + wi * 4 + 2, redc[0] + redc[1] + redc[2] + redc[3]);
    }
}

// ---------------------------------------------------------------------------
// conv1: i8 MFMA, no K-loop, block = 1 image. Epilogue quantizes a1 with S1
// and writes i8 lo/hi in conv2's swizzled X-interior layout; tracks amax(a1).
// ---------------------------------------------------------------------------
__global__ __launch_bounds__(256) void conv1_i8(
        const float* __restrict__ x,
        const signed char* __restrict__ w1b,   // [2][64 co][64 k]
        const float* __restrict__ bias,
        const double* __restrict__ scr,        // base scr
        const int* __restrict__ amax_x,
        int* __restrict__ amax_out,            // amax1
        signed char* __restrict__ a1q) {
    constexpr int PL = 3472;                   // plane stride bytes
    __shared__ __align__(16) char X[2 * PL];
    __shared__ float redm[4];

    const int b = blockIdx.x;
    const int tid = threadIdx.x;
    const float amx = fmaxf(__int_as_float(*amax_x), 1e-30f);
    const float S = 32512.0f / amx;
    const float S1 = calc_S1(scr, __int_as_float(*amax_x));

    for (int i = tid; i < 2 * PL / 16; i += 256)
        ((int4*)X)[i] = make_int4(0, 0, 0, 0);
    __syncthreads();

    for (int i = tid; i < 768; i += 256) {
        const float4 v = ((const float4*)(x + (long)b * 3072))[i];
        const int e = i * 4;
        const int ci = e >> 10;
        const int rem = e & 1023;
        const int h = rem >> 5, w = rem & 31;
        const int base = ci * 1156 + (h + 1) * 34 + (w + 1);
        const float f[4] = {v.x, v.y, v.z, v.w};
        #pragma unroll
        for (int j = 0; j < 4; j++) {
            const int q = __float2int_rn(f[j] * S);
            const int ql = (q << 24) >> 24;
            const int qh = (q - ql) >> 8;
            X[base + j] = (char)ql;
            X[PL + base + j] = (char)qh;
        }
    }
    __syncthreads();

    const int lane = tid & 63;
    const int wid = tid >> 6;
    const int lm = lane & 15;
    const int kg = lane >> 4;

    const int poff = (kg >= 2) ? PL : 0;
    int cst[16];
    #pragma unroll
    for (int j = 0; j < 16; j++) {
        const int kp = (kg & 1) * 16 + j;
        cst[j] = (kp < 27)
                     ? ((kp / 9) * 1156 + ((kp % 9) / 3) * 34 + (kp % 9) % 3)
                     : 0;
    }

    i32x4 BL[4], BH[4];
    #pragma unroll
    for (int nt = 0; nt < 4; nt++) {
        const int co = nt * 16 + lm;
        BL[nt] = *(const i32x4*)(w1b + (long)co * 64 + kg * 16);
        BH[nt] = *(const i32x4*)(w1b + 4096 + (long)co * 64 + kg * 16);
    }

    const double c2 = scr[2];
    const float alpha = (float)(scr[1] / (c2 > 1.0 ? c2 : 1.0));
    const float dq = alpha / S;
    float tmax = 0.f;
    signed char* yb = a1q + (long)b * 32768;

    for (int tt = 0; tt < 16; ++tt) {
        const int t = wid * 16 + tt;
        const int pp = t * 4 + (lm >> 2);
        const int sub = lm & 3;
        const int h = 2 * (pp >> 4) + (sub >> 1);
        const int w = 2 * (pp & 15) + (sub & 1);
        const int base = poff + h * 34 + w;
        unsigned d[4] = {0u, 0u, 0u, 0u};
        #pragma unroll
        for (int j = 0; j < 16; j++) {
            const unsigned byte = (unsigned char)X[base + cst[j]];
            d[j >> 2] |= byte << ((j & 3) * 8);
        }
        i32x4 Af;
        Af[0] = (int)d[0]; Af[1] = (int)d[1];
        Af[2] = (int)d[2]; Af[3] = (int)d[3];

        const int opp = t * 4 + kg;
        const int ho = opp >> 4, wo = opp & 15;
        signed char* yrow = yb + ((long)ho * 2048) + wo * 64;
        #pragma unroll
        for (int nt = 0; nt < 4; nt++) {
            i32x4 aL = 0, aH = 0;
            aL = __builtin_amdgcn_mfma_i32_16x16x64_i8(Af, BL[nt], aL, 0, 0, 0);
            aH = __builtin_amdgcn_mfma_i32_16x16x64_i8(Af, BH[nt], aH, 0, 0, 0);
            const int s0 = aH[0] * 256 + aL[0];
            const int s1 = aH[1] * 256 + aL[1];
            const int s2 = aH[2] * 256 + aL[2];
            const int s3 = aH[3] * 256 + aL[3];
            int sm = s0 > s1 ? s0 : s1;
            const int sn = s2 > s3 ? s2 : s3;
            sm = sm > sn ? sm : sn;
            const int co = nt * 16 + lm;
            const float o = fmaxf(dq * (float)sm + bias[co], 0.f);
            tmax = fmaxf(tmax, o);
            const int q = (int)(o * S1 + 0.5f);      // o >= 0
            const int ql = (q << 24) >> 24;
            const int qh = (q + 128) >> 8;            // == (q - ql) >> 8
            const int slot = (nt + ((wo + 1) >> 1) + 2 * (ho + 1)) & 3;
            const int off = slot * 16 + lm;           // co & 15 == lm
            yrow[off] = (char)ql;
            yrow[1024 + off] = (char)qh;
        }
    }

    #pragma unroll
    for (int off = 32; off > 0; off >>= 1)
        tmax = fmaxf(tmax, __shfl_down(tmax, off, 64));
    if (lane == 0) redm[wid] = tmax;
    __syncthreads();
    if (tid == 0) {
        float m = fmaxf(fmaxf(redm[0], redm[1]), fmaxf(redm[2], redm[3]));
        atomicMax(amax_out, __float_as_int(m));
    }
}

// ---------------------------------------------------------------------------
// int8 MFMA conv, R22 tiles: MT=4 x NT=4, 128 AGPR acc, 2 blocks/CU.
// MODE 0 (conv2): a1q prequant input, direct-X DMA staging (one barrier),
//   epilogue -> a2q i8 pairs (S2) + amax(a2) atomic.
// MODE 1 (conv3): a2q prequant input, 16 DMAs -> RAW2 + conflict-free b32
//   LDS->LDS swizzle copy; epilogue -> a3q i8 pairs (S3) for fc1.
// ---------------------------------------------------------------------------
template <int CI, int HI, int CO, int HB, int WM, int WN, int MODE, int WIDX>
__global__ __launch_bounds__(256, 2) void conv_i8(
        const signed char* __restrict__ xin,
        const signed char* __restrict__ wp,     // [9][CO][CI] int8 signs
        const float* __restrict__ bias,
        const double* __restrict__ scr,         // base scr
        const int* __restrict__ amax_x,         // amax(x)  (S1)
        const int* __restrict__ amax_1,         // amax(a1) (S2)
        int* __restrict__ amax_2,               // amax(a2) (S3; MODE0 out)
        void* __restrict__ yout) {
    constexpr int CH8 = CI / 64;
    constexpr int NITER = 9 * CH8;
    constexpr int HR = HI / HB;
    constexpr int ROWS = HR + 2;
    constexpr int COLS = HI + 2;
    constexpr int NPIX = ROWS * COLS;
    constexpr int PSTR = NPIX * 64 + 32;    // bytes per g-plane
    constexpr int PO = HI / 2;
    constexpr int POR = HR / 2;
    constexpr int MT = 4, NT = 4;
    constexpr int NPL = 2 * CH8;
    constexpr int RWQ = HI * 64 * 2;        // MODE0 prequant row bytes
    static_assert(WM * WN == 4, "4 waves");
    static_assert(WM * 64 == HR * HI, "M covers slab pixels");
    static_assert(WN * 64 == CO, "N covers all co");
    static_assert(MODE != 0 || (CI == 64 && RWQ == 2048), "conv2 shape");
    static_assert(MODE != 1 || (CI == 128 && HB == 1), "conv3 shape");
    static_assert(HB <= 2, "row compaction assumes <=1 invalid row per end");
    static_assert((COLS & 1) == 0, "swizzle parity uses even COLS");

    __shared__ __align__(16) char X[NPL * PSTR];
    __shared__ __align__(16) char RAW2[(MODE == 1) ? 16384 : 16];
    __shared__ float redm[4];

    const int bimg = blockIdx.x / HB;
    const int hb = blockIdx.x % HB;
    const int tid = threadIdx.x;
    const int lane = tid & 63;
    const int wid = tid >> 6;

    const float S_in = (MODE == 0)
                           ? calc_S1(scr, __int_as_float(*amax_x))
                           : calc_S2(scr, __int_as_float(*amax_1));

    const int rlo = (hb == 0) ? 1 : 0;
    const int rhi = (hb == HB - 1) ? (ROWS - 1) : ROWS;

    if (MODE == 0) {
        // direct-X DMA: interior row = HI*64 = 1024 B per plane
        for (int r = rlo; r < rhi; r++) {
            #pragma unroll
            for (int pl = 0; pl < 2; pl++) {
                if (wid == ((r * 2 + pl) & 3)) {
                    const int h = hb * HR + r - 1;       // in range
                    const signed char* src = xin +
                        (long)(bimg * HI + h) * RWQ + pl * 1024 + lane * 16;
                    GLOAD_LDS16(src, &X[pl * PSTR + (r * COLS + 1) * 64]);
                }
            }
        }
    } else {
        // 16 DMAs -> RAW2 (image chunk is 16 KB contiguous)
        #pragma unroll
        for (int j = 0; j < 16; j++) {
            if (wid == (j & 3)) {
                const signed char* src = xin + (long)bimg * 16384 +
                                         j * 1024 + lane * 16;
                GLOAD_LDS16(src, &RAW2[j * 1024]);
            }
        }
    }

    // halo zero: side cols of all rows + interior of non-DMA'd halo rows.
    {
        const int nfull = ((hb == 0) ? 1 : 0) + ((hb == HB - 1) ? 1 : 0);
        const int NP1 = ROWS * 2;
        const int NPZ = NP1 + nfull * (COLS - 2);
        for (int i = tid; i < NPZ * NPL * 4; i += 256) {
            const int u = i & 3;
            const int t = i >> 2;
            const int g = t % NPL;
            const int e = t / NPL;
            int p;
            if (e < NP1) {
                const int row = e >> 1;
                p = row * COLS + ((e & 1) ? (COLS - 1) : 0);
            } else {
                const int e2 = e - NP1;
                const int inFirst = (hb == 0) && (e2 < COLS - 2);
                const int fr = inFirst ? 0 : (ROWS - 1);
                const int cc = inFirst ? e2
                                       : (e2 - ((hb == 0) ? (COLS - 2) : 0));
                p = fr * COLS + 1 + cc;
            }
            *(int4*)&X[g * PSTR + p * 64 + u * 16] = make_int4(0, 0, 0, 0);
        }
    }

    if (MODE == 1) {
        __syncthreads();    // RAW2 ready (drains DMA)
        // conflict-free b32 LDS->LDS copy RAW2 -> swizzled X interior.
        #pragma unroll
        for (int k = 0; k < 16; k++) {
            const int v = tid + k * 256;
            const int h = v >> 9;
            const int r = v & 511;
            const int g = r >> 7;
            const int b4 = (r & 127) << 2;
            const unsigned d = *(const unsigned*)&RAW2[v << 2];
            *(unsigned*)&X[g * PSTR + ((h + 1) * COLS + 1) * 64 + b4] = d;
        }
    }
    __syncthreads();

    const int wm = (WM == 1) ? 0 : (wid >> 1);
    const int wn = (WM == 1) ? wid : (wid & 1);
    const int lm = lane & 15;
    const int kg = lane >> 4;

    // pq = (p<<6) | (h&1)<<3 | (w&7)
    int pq[MT];
    #pragma unroll
    for (int mt = 0; mt < MT; mt++) {
        const int m = (wm * MT + mt) * 16 + lm;
        const int pp = m >> 2, sub = m & 3;
        const int lph = pp / PO, lpw = pp % PO;
        const int h = 2 * lph + (sub >> 1);
        const int w = 2 * lpw + (sub & 1);
        pq[mt] = ((h * COLS + w) << 6) | ((h & 1) << 3) | (w & 7);
    }
    const signed char* bp[NT];
    #pragma unroll
    for (int nt = 0; nt < NT; nt++) {
        const int co = (wn * NT + nt) * 16 + lm;
        bp[nt] = wp + (long)co * CI + kg * 16;
    }

    i32x4 accL[MT][NT], accH[MT][NT];
    #pragma unroll
    for (int mt = 0; mt < MT; mt++)
        #pragma unroll
        for (int nt = 0; nt < NT; nt++) { accL[mt][nt] = 0; accH[mt][nt] = 0; }

    i32x4 Bb[2][NT];
    #pragma unroll
    for (int nt = 0; nt < NT; nt++) Bb[0][nt] = *(const i32x4*)(bp[nt]);

    #pragma unroll 2
    for (int it = 0; it < NITER; ++it) {
        const int cur = it & 1, nxt = cur ^ 1;
        if (it + 1 < NITER) {
            const int it1 = it + 1;
            const int tap = it1 / CH8, ch1 = it1 % CH8;
            const int woff = tap * CO * CI + ch1 * 64;
            #pragma unroll
            for (int nt = 0; nt < NT; nt++)
                Bb[nxt][nt] = *(const i32x4*)(bp[nt] + woff);
        }
        const int tap = it / CH8, ch = it % CH8;
        const int ty = tap / 3, tx = tap % 3;       // wave-uniform (SALU)
        const int DT = (ty * COLS + tx) << 6;
        const int typ = ty & 1;
        int ao[MT];
        #pragma unroll
        for (int mt = 0; mt < MT; mt++) {
            const int q = pq[mt];
            const int slot = (kg + ((((q >> 3) & 1) + typ) & 1) * 2 +
                              (((q & 7) + tx) >> 1)) & 3;
            ao[mt] = (q & ~63) + DT + (slot << 4);
        }
        {
            i32x4 Af[MT];
            #pragma unroll
            for (int mt = 0; mt < MT; mt++)
                Af[mt] = *(const i32x4*)&X[ch * PSTR + ao[mt]];
            #pragma unroll
            for (int mt = 0; mt < MT; mt++)
                #pragma unroll
                for (int nt = 0; nt < NT; nt++)
                    accL[mt][nt] = __builtin_amdgcn_mfma_i32_16x16x64_i8(
                        Af[mt], Bb[cur][nt], accL[mt][nt], 0, 0, 0);
        }
        {
            i32x4 Af[MT];
            #pragma unroll
            for (int mt = 0; mt < MT; mt++)
                Af[mt] = *(const i32x4*)&X[(CH8 + ch) * PSTR + ao[mt]];
            #pragma unroll
            for (int mt = 0; mt < MT; mt++)
                #pragma unroll
                for (int nt = 0; nt < NT; nt++)
                    accH[mt][nt] = __builtin_amdgcn_mfma_i32_16x16x64_i8(
                        Af[mt], Bb[cur][nt], accH[mt][nt], 0, 0, 0);
        }
    }

    // epilogue: sum = 256*accH + accL (exact i32); pool in int; dq+bias+relu
    const double* wst = scr + WIDX * 4;
    const double c2 = wst[2];
    const float alpha = (float)(wst[1] / (c2 > 1.0 ? c2 : 1.0));
    const float dq = alpha / S_in;
    if (MODE == 0) {
        // write a2q: [img][h:8][g:4][w*64 + slot*16 + (ci&15)] i8 + amax2
        const float S2 = calc_S2(scr, __int_as_float(*amax_1));
        signed char* oq = (signed char*)yout;
        float tmax = 0.f;
        #pragma unroll
        for (int mt = 0; mt < MT; mt++) {
            const int pp = (wm * MT + mt) * 4 + kg;
            const int lph = pp / PO, lpw = pp % PO;
            const int h = hb * POR + lph;
            const int w = lpw;
            #pragma unroll
            for (int nt = 0; nt < NT; nt++) {
                const int co2 = (wn * NT + nt) * 16 + lm;
                const i32x4 aL = accL[mt][nt], aH = accH[mt][nt];
                int s0 = aH[0] * 256 + aL[0];
                int s1 = aH[1] * 256 + aL[1];
                int s2 = aH[2] * 256 + aL[2];
                int s3 = aH[3] * 256 + aL[3];
                int sm = s0 > s1 ? s0 : s1;
                int sn = s2 > s3 ? s2 : s3;
                sm = sm > sn ? sm : sn;
                const float o = fmaxf(dq * (float)sm + bias[co2], 0.f);
                tmax = fmaxf(tmax, o);
                const int q = (int)(o * S2 + 0.5f);   // o >= 0
                const int ql = (q << 24) >> 24;
                const int qh = (q + 128) >> 8;
                const int slot = (((co2 >> 4) & 3) + ((w + 1) >> 1) +
                                  2 * (h + 1)) & 3;
                const long base = (long)bimg * 16384 + h * 2048 +
                                  (co2 >> 6) * 512 + w * 64 + slot * 16 +
                                  (co2 & 15);
                oq[base] = (char)ql;
                oq[base + 1024] = (char)qh;
            }
        }
        #pragma unroll
        for (int off = 32; off > 0; off >>= 1)
            tmax = fmaxf(tmax, __shfl_down(tmax, off, 64));
        if (lane == 0) redm[wid] = tmax;
        __syncthreads();
        if (tid == 0) {
            float m = fmaxf(fmaxf(redm[0], redm[1]), fmaxf(redm[2], redm[3]));
            atomicMax(amax_2, __float_as_int(m));
        }
    } else {
        // write a3q: [img][px:16][lo 256 | hi 256] i8 (fc1 layout)
        const float S3 = calc_S3(scr, __int_as_float(*amax_2));
        signed char* oq = (signed char*)yout;
        #pragma unroll
        for (int mt = 0; mt < MT; mt++) {
            const int pp = (wm * MT + mt) * 4 + kg;
            const int lph = pp / PO, lpw = pp % PO;
            const int gpp = (hb * POR + lph) * PO + lpw;
            signed char* yr = oq + (long)bimg * 8192 + gpp * 512;
            #pragma unroll
            for (int nt = 0; nt < NT; nt++) {
                const int co = (wn * NT + nt) * 16 + lm;
                const i32x4 aL = accL[mt][nt], aH = accH[mt][nt];
                int s0 = aH[0] * 256 + aL[0];
                int s1 = aH[1] * 256 + aL[1];
                int s2 = aH[2] * 256 + aL[2];
                int s3 = aH[3] * 256 + aL[3];
                int sm = s0 > s1 ? s0 : s1;
                int sn = s2 > s3 ? s2 : s3;
                sm = sm > sn ? sm : sn;
                const float o = fmaxf(dq * (float)sm + bias[co], 0.f);
                const int q = (int)(o * S3 + 0.5f);   // o >= 0
                const int ql = (q << 24) >> 24;
                const int qh = (q + 128) >> 8;
                yr[co] = (char)ql;          // lo plane at +0
                yr[256 + co] = (char)qh;    // hi plane at +256
            }
        }
    }
}

// ---------------------------------------------------------------------------
// FUSED fc1+fc2 (no split-K, no parts): 64 blocks x 512 threads (8 waves).
// Block = 16 images (one MFMA M-tile) x all 256 channels x K=4096 x 2
// planes. Wave wn covers channels wn*32 + nt*16 + lm (NT=2). Exact integer
// accumulation: |256*accH + accL| <= 256*4096*127 + 4096*127 < 2^28.
// h = relu(alpha*sum/S3 + bf1) -> hbuf[16][257] (pad: conflict-free fc2
// read), barrier, threads 0..159 compute out[img][k] scalar.
// ---------------------------------------------------------------------------
__global__ __launch_bounds__(512) void fc1fc2_i8(
        const signed char* __restrict__ A,    // a3q [1024][16px][lo|hi] 8192B
        const signed char* __restrict__ Bw,   // wtf1b8 [256][4096] i8
        const double* __restrict__ scr,       // base scr
        const int* __restrict__ amax_2,       // amax(a2) for S3
        const float* __restrict__ bf1v,
        const signed char* __restrict__ wtf2b8,
        const float* __restrict__ bf2v,
        float* __restrict__ out) {
    __shared__ float hbuf[16][257];

    const int m0 = blockIdx.x * 16;
    const int tid = threadIdx.x;
    const int lane = tid & 63, wn = tid >> 6;     // 8 waves
    const int lm = lane & 15, kg = lane >> 4;

    const signed char* ap = A + (long)(m0 + lm) * 8192;
    const signed char* bp[2];
    #pragma unroll
    for (int nt = 0; nt < 2; nt++)
        bp[nt] = Bw + (long)(wn * 32 + nt * 16 + lm) * 4096 + kg * 16;

    i32x4 accL[2], accH[2];
    #pragma unroll
    for (int nt = 0; nt < 2; nt++) { accL[nt] = 0; accH[nt] = 0; }

    #pragma unroll 4
    for (int ch = 0; ch < 64; ++ch) {
        const int aoff = (ch >> 2) * 512 + ((ch & 3) << 6) + kg * 16;
        const i32x4 Al = *(const i32x4*)(ap + aoff);          // lo (+0)
        const i32x4 Ah = *(const i32x4*)(ap + aoff + 256);    // hi (+256)
        i32x4 Bb[2];
        #pragma unroll
        for (int nt = 0; nt < 2; nt++)
            Bb[nt] = *(const i32x4*)(bp[nt] + ch * 64);
        #pragma unroll
        for (int nt = 0; nt < 2; nt++) {
            accL[nt] = __builtin_amdgcn_mfma_i32_16x16x64_i8(
                Al, Bb[nt], accL[nt], 0, 0, 0);
            accH[nt] = __builtin_amdgcn_mfma_i32_16x16x64_i8(
                Ah, Bb[nt], accH[nt], 0, 0, 0);
        }
    }

    // h = relu(alpha * sum / S3 + bias)
    const double c2 = scr[14];
    const float alpha = (float)(scr[13] / (c2 > 1.0 ? c2 : 1.0));
    const float S3 = calc_S3(scr, __int_as_float(*amax_2));
    #pragma unroll
    for (int nt = 0; nt < 2; nt++) {
        const int ch = wn * 32 + nt * 16 + lm;
        const float bj = bf1v[ch];
        #pragma unroll
        for (int r = 0; r < 4; r++) {
            const int img = kg * 4 + r;
            const int sum = accH[nt][r] * 256 + accL[nt][r];
            hbuf[img][ch] = fmaxf(alpha * (float)sum / S3 + bj, 0.f);
        }
    }
    __syncthreads();

    // fc2: 160 outputs (16 img x 10 k), scalar over 256 channels
    if (tid < 160) {
        const int img = tid / 10;
        const int k = tid % 10;
        const double c4 = scr[18];
        const float alpha4 = (float)(scr[17] / (c4 > 1.0 ? c4 : 1.0));
        const signed char* wr = wtf2b8 + k * 256;
        float acc = 0.f;
        #pragma unroll 8
        for (int c = 0; c < 256; c++)
            acc += hbuf[img][c] * (float)wr[c];
        out[(long)(m0 + img) * 10 + k] = acc * alpha4 + bf2v[k];
    }
}

extern "C" void kernel_launch(void* const* d_in, const int* in_sizes, int n_in,
                              void* d_out, int out_size, void* d_ws, size_t ws_size,
                              hipStream_t stream) {
    const float* x   = (const float*)d_in[0];
    const float* w1  = (const float*)d_in[1];
    const float* b1  = (const float*)d_in[2];
    const float* w2  = (const float*)d_in[3];
    const float* b2  = (const float*)d_in[4];
    const float* w3  = (const float*)d_in[5];
    const float* b3  = (const float*)d_in[6];
    const float* wf1 = (const float*)d_in[7];
    const float* bf1 = (const float*)d_in[8];
    const float* wf2 = (const float*)d_in[9];
    const float* bf2 = (const float*)d_in[10];
    float* out = (float*)d_out;
    float* ws = (float*)d_ws;

    const int B = 1024;

    signed char*    w1b    = (signed char*)(ws + WS_W1B);
    signed char*    w2p8   = (signed char*)(ws + WS_W2P);
    signed char*    w3p8   = (signed char*)(ws + WS_W3P);
    signed char*    wtf1b8 = (signed char*)(ws + WS_WTF1);
    signed char*    wtf2b8 = (signed char*)(ws + WS_WTF2);
    signed char*    a1q    = (signed char*)(ws + WS_A1);
    signed char*    a2q    = (signed char*)(ws + WS_A2);
    signed char*    a3q    = (signed char*)(ws + WS_A3);
    double*         scr    = (double*)(ws + WS_SCR);
    int*            iscr   = (int*)(scr + 20);
    int*            amaxx  = iscr;          // amax(x)
    int*            amax1  = iscr + 1;      // amax(a1)
    int*            amax2  = iscr + 2;      // amax(a2)

    hipMemsetAsync(scr, 0, 26 * sizeof(double), stream);

    TernArgs ta;
    ta.w[0] = w1;  ta.n[0] = 64 * 27;
    ta.w[1] = w2;  ta.n[1] = 128 * 64 * 9;
    ta.w[2] = w3;  ta.n[2] = 256 * 128 * 9;
    ta.w[3] = wf1; ta.n[3] = 256 * 4096;
    ta.w[4] = wf2; ta.n[4] = 10 * 256;
    ta.w[5] = x;   ta.n[5] = 1024 * 3 * 32 * 32;   // amax(x)

    hipLaunchKernelGGL(tern_stats1, dim3(128, 6), dim3(256), 0, stream, ta, scr);
    hipLaunchKernelGGL(tern_stats2, dim3(128, 6), dim3(256), 0, stream,
                       ta, b1, b2, b3, w1b, w2p8, w3p8, wtf1b8, wtf2b8, scr);

    // conv1: i8 MFMA -> prequantized a1q + amax1
    hipLaunchKernelGGL(conv1_i8, dim3(B), dim3(256), 0, stream,
                       x, w1b, b1, scr, amaxx, amax1, a1q);

    // conv2: CI=64, HI=16, CO=128, HB=2 -> 2048 blocks; a2q out + amax2
    hipLaunchKernelGGL((conv_i8<64, 16, 128, 2, 2, 2, 0, 1>), dim3(B * 2),
                       dim3(256), 0, stream, a1q, w2p8, b2, scr, amaxx,
                       amax1, amax2, a2q);

    // conv3: CI=128, HI=8, CO=256, HB=1 -> 1024 blocks; a3q i8 out (S3)
    hipLaunchKernelGGL((conv_i8<128, 8, 256, 1, 1, 4, 1, 2>), dim3(B),
                       dim3(256), 0, stream, a2q, w3p8, b3, scr, amaxx,
                       amax1, amax2, a3q);

    // fused fc1+fc2: 64 blocks x 512 threads, no parts round-trip
    hipLaunchKernelGGL(fc1fc2_i8, dim3(64), dim3(512), 0, stream,
                       a3q, wtf1b8, scr, amax2, bf1, wtf2b8, bf2, out);
}

// Round 15
// 259.120 us; speedup vs baseline: 1.1751x; 1.1751x over previous
//
#include <hip/hip_runtime.h>
#include <hip/hip_bf16.h>

// ---------------------------------------------------------------------------
// TernaryCIFAR10Net on MI355X — Round 30 (= verified R28, 259.9 us):
//   R29 post-mortem: fc1+fc2 fusion starved occupancy (64 blocks, 5% occ,
//   62.7 us). The split-K parts design is structurally right: parallelism
//   beats traffic at these sizes. Reverted to the best verified config:
//   - stats1 + stats2 (fused sign-packing + w1b zero + nnz/bias maxima)
//   - conv1_i8: prequant a1q in conv2's swizzled layout (S1 bound-scale)
//   - conv2 (conv_i8 MODE0): direct-X DMA staging, a2q prequant out (S2)
//   - conv3 (conv_i8 MODE1): DMA->RAW2 + LDS swizzle copy, a3q out (S3)
//   - fc1_i8: pure-integer MFMA 128x128 split-K=16
//   - fc2_fused: parts reduce + fc2 (alpha4 at the end)
// ---------------------------------------------------------------------------

typedef __attribute__((ext_vector_type(8))) short short8;
typedef __attribute__((ext_vector_type(4))) float f32x4;
typedef __attribute__((ext_vector_type(4))) int i32x4;

#define GLOAD_LDS16(g, l)                                              \
    __builtin_amdgcn_global_load_lds(                                  \
        (const __attribute__((address_space(1))) void*)(g),            \
        (__attribute__((address_space(3))) void*)(l), 16, 0, 0)

__device__ __forceinline__ unsigned short f2bf(float x) {
    unsigned u = __float_as_uint(x);
    return (unsigned short)((u + 0x7fffu + ((u >> 16) & 1u)) >> 16);  // RNE
}
__device__ __forceinline__ float bf2f(unsigned short b) {
    return __uint_as_float(((unsigned)b) << 16);
}

// int side-slots at scr+20: [0]=amaxx [1]=amax1 [2]=amax2
//                           [3]=nnz1 [4]=nnz2 [5]=nnz3
//                           [6]=bmax1 [7]=bmax2 [8]=bmax3  (float bits)
// Scales: identical instruction sequence at every use site (determinism).
__device__ __forceinline__ float calc_S1(const double* __restrict__ scr,
                                         float amaxx) {
    const int* ii = (const int*)(scr + 20);
    const double c2 = scr[2];
    const float alpha1 = (float)(scr[1] / (c2 > 1.0 ? c2 : 1.0));
    const float ub = alpha1 * (float)ii[3] * amaxx + __int_as_float(ii[6]);
    return 32512.0f / fmaxf(ub, 1e-30f);
}
__device__ __forceinline__ float calc_S2(const double* __restrict__ scr,
                                         float amax1) {
    const int* ii = (const int*)(scr + 20);
    const double c2 = scr[6];
    const float alpha2 = (float)(scr[5] / (c2 > 1.0 ? c2 : 1.0));
    const float ub = alpha2 * (float)ii[4] * amax1 + __int_as_float(ii[7]);
    return 32512.0f / fmaxf(ub, 1e-30f);
}
__device__ __forceinline__ float calc_S3(const double* __restrict__ scr,
                                         float amax2) {
    const int* ii = (const int*)(scr + 20);
    const double c2 = scr[10];
    const float alpha3 = (float)(scr[9] / (c2 > 1.0 ? c2 : 1.0));
    const float ub = alpha3 * (float)ii[5] * amax2 + __int_as_float(ii[8]);
    return 32512.0f / fmaxf(ub, 1e-30f);
}

// workspace layout (4-byte units)
#define WS_W1B   0
#define N_W1B    2048                  // 8192 B: [2][64 co][64 k] i8 signs
#define WS_W2P   (WS_W1B + N_W1B)
#define N_W2P    (9*128*64)
#define WS_W3P   (WS_W2P + N_W2P)
#define N_W3P    (9*256*128)
#define WS_WTF1  (WS_W3P + N_W3P)
#define N_WTF1   (256*4096)            // region (i8 signs use 1 MB of it)
#define WS_WTF2  (WS_WTF1 + N_WTF1)
#define N_WTF2   (10*256)
#define WS_A1    (WS_WTF2 + N_WTF2)
#define N_A1     (1024*256*64)         // region: a1q (32MB) / parts (16MB)
#define WS_A2    (WS_A1 + N_A1)
#define N_A2     (1024*64*128)         // region: a2q (16MB)
#define WS_A3    (WS_A2 + N_A2)
#define N_A3     (1024*16*256)         // region: a3q (8MB)
#define WS_F1    (WS_A3 + N_A3)
#define N_F1     (1024*256)
#define WS_SCR   (WS_F1 + N_F1)

#define FC1_S    16

struct TernArgs {
    const float* w[6];
    int n[6];
};

// ---------------------------------------------------------------------------
// Stats pass 1: wi<5 -> sum|w|; wi==5 -> amax(x) -> iscr[0].
// ---------------------------------------------------------------------------
__global__ void tern_stats1(TernArgs ta, double* __restrict__ scr) {
    const int wi = blockIdx.y;
    const float* __restrict__ w = ta.w[wi];
    const int n = ta.n[wi];
    __shared__ double red[4];
    const int lane = threadIdx.x & 63, wv = threadIdx.x >> 6;
    if (wi == 5) {
        float m = 0.f;
        for (int i = blockIdx.x * blockDim.x + threadIdx.x; i < n;
             i += gridDim.x * blockDim.x)
            m = fmaxf(m, fabsf(w[i]));
        #pragma unroll
        for (int off = 32; off > 0; off >>= 1)
            m = fmaxf(m, __shfl_down(m, off, 64));
        if (lane == 0) red[wv] = (double)m;
        __syncthreads();
        if (threadIdx.x == 0) {
            float mm = (float)fmax(fmax(red[0], red[1]), fmax(red[2], red[3]));
            atomicMax((int*)(scr + 20), __float_as_int(mm));
        }
        return;
    }
    double s = 0.0;
    for (int i = blockIdx.x * blockDim.x + threadIdx.x; i < n;
         i += gridDim.x * blockDim.x)
        s += (double)fabsf(w[i]);
    #pragma unroll
    for (int off = 32; off > 0; off >>= 1) s += __shfl_down(s, off, 64);
    if (lane == 0) red[wv] = s;
    __syncthreads();
    if (threadIdx.x == 0)
        atomicAdd(scr + wi * 4, red[0] + red[1] + red[2] + red[3]);
}

// ---------------------------------------------------------------------------
// Stats pass 2 + fused sign writer. wi<5: masked sum/count AND packed sign
// stores in the same element loop; wi==0 additionally zeroes w1b's non-sign
// bytes (disjoint from sign writes -> race-free; replaces the w1b memset).
// wi==5: nnz/bias-max pass (wave-per-row, atomicMax into int slots).
// ---------------------------------------------------------------------------
__global__ void tern_stats2(TernArgs ta,
                            const float* __restrict__ b1v,
                            const float* __restrict__ b2v,
                            const float* __restrict__ b3v,
                            signed char* __restrict__ w1b,
                            signed char* __restrict__ w2p8,
                            signed char* __restrict__ w3p8,
                            signed char* __restrict__ wtf1b8,
                            signed char* __restrict__ wtf2b8,
                            double* __restrict__ scr) {
    const int wi = blockIdx.y;
    const int lane = threadIdx.x & 63, wv = threadIdx.x >> 6;

    if (wi == 5) {
        int* ii = (int*)(scr + 20);
        const int gw = blockIdx.x * 4 + wv;     // global wave id
        if (gw < 64) {                          // w1 row gw (27 elems)
            const float d = (float)(0.7 * scr[0] / 1728.0);
            const float* row = ta.w[0] + gw * 27;
            int c = (lane < 27) ? (fabsf(row[lane]) > d ? 1 : 0) : 0;
            #pragma unroll
            for (int off = 32; off > 0; off >>= 1)
                c += __shfl_down(c, off, 64);
            if (lane == 0) atomicMax(ii + 3, c);
        } else if (gw < 192) {                  // w2 row gw-64 (576)
            const float d = (float)(0.7 * scr[4] / 73728.0);
            const float* row = ta.w[1] + (long)(gw - 64) * 576;
            int c = 0;
            for (int k = lane; k < 576; k += 64)
                c += (fabsf(row[k]) > d) ? 1 : 0;
            #pragma unroll
            for (int off = 32; off > 0; off >>= 1)
                c += __shfl_down(c, off, 64);
            if (lane == 0) atomicMax(ii + 4, c);
        } else if (gw < 448) {                  // w3 row gw-192 (1152)
            const float d = (float)(0.7 * scr[8] / 294912.0);
            const float* row = ta.w[2] + (long)(gw - 192) * 1152;
            int c = 0;
            for (int k = lane; k < 1152; k += 64)
                c += (fabsf(row[k]) > d) ? 1 : 0;
            #pragma unroll
            for (int off = 32; off > 0; off >>= 1)
                c += __shfl_down(c, off, 64);
            if (lane == 0) atomicMax(ii + 5, c);
        } else if (gw < 451) {                  // biases
            const float* bv = (gw == 448) ? b1v : (gw == 449) ? b2v : b3v;
            const int nb = (gw == 448) ? 64 : (gw == 449) ? 128 : 256;
            float m = 0.f;
            for (int k = lane; k < nb; k += 64) m = fmaxf(m, fabsf(bv[k]));
            #pragma unroll
            for (int off = 32; off > 0; off >>= 1)
                m = fmaxf(m, __shfl_down(m, off, 64));
            if (lane == 0)
                atomicMax(ii + 6 + (gw - 448), __float_as_int(m));
        }
        return;
    }

    const float* __restrict__ w = ta.w[wi];
    const int n = ta.n[wi];
    const float delta = (float)(0.7 * scr[wi * 4] / (double)n);

    if (wi == 0) {
        // zero w1b non-sign bytes (sign slots written by the loop below;
        // disjoint byte sets -> no ordering needed)
        const int z0 = blockIdx.x * blockDim.x + threadIdx.x;
        const int zstride = gridDim.x * blockDim.x;
        for (int i = z0; i < 8192; i += zstride) {
            const int k = i & 63;
            const int plane = i >> 12;
            const bool sign_slot = plane == 0 ? (k < 27)
                                              : (k >= 32 && k < 59);
            if (!sign_slot) w1b[i] = 0;
        }
    }

    double ms = 0.0, cnt = 0.0;
    for (int i = blockIdx.x * blockDim.x + threadIdx.x; i < n;
         i += gridDim.x * blockDim.x) {
        const float v = w[i];
        const float a = fabsf(v);
        const bool mk = (a > delta);
        if (mk) { ms += (double)a; cnt += 1.0; }
        const signed char s = mk ? (v > 0.0f ? 1 : -1) : 0;
        if (wi == 0) {                       // n = 1728 = 64*27
            const int co = i / 27;
            const int kp = i % 27;           // ci*9 + tap
            w1b[co * 64 + kp] = s;           // BL, k = kp
            w1b[4096 + co * 64 + 32 + kp] = s;   // BH, k = 32+kp
        } else if (wi == 1 || wi == 2) {
            const int CIc = (wi == 1) ? 64 : 128;
            const int COc = (wi == 1) ? 128 : 256;
            signed char* dst = (wi == 1) ? w2p8 : w3p8;
            const int co = i / (CIc * 9);
            const int r = i % (CIc * 9);
            const int ci = r / 9, tap = r % 9;
            dst[(tap * COc + co) * CIc + ci] = s;
        } else if (wi == 3) {                // fc1 signs: k' = px*256 + c
            const int j = i >> 12;
            const int k = i & 4095;
            const int px = k & 15, c = k >> 4;
            wtf1b8[(long)j * 4096 + px * 256 + c] = s;
        } else {                             // wi == 4: fc2 signs
            wtf2b8[i] = s;
        }
    }
    #pragma unroll
    for (int off = 32; off > 0; off >>= 1) {
        ms += __shfl_down(ms, off, 64);
        cnt += __shfl_down(cnt, off, 64);
    }
    __shared__ double redm[4], redc[4];
    if (lane == 0) { redm[wv] = ms; redc[wv] = cnt; }
    __syncthreads();
    if (threadIdx.x == 0) {
        atomicAdd(scr + wi * 4 + 1, redm[0] + redm[1] + redm[2] + redm[3]);
        atomicAdd(scr + wi * 4 + 2, redc[0] + redc[1] + redc[2] + redc[3]);
    }
}

// ---------------------------------------------------------------------------
// conv1: i8 MFMA, no K-loop, block = 1 image. Epilogue quantizes a1 with S1
// and writes i8 lo/hi in conv2's swizzled X-interior layout; tracks amax(a1)
// (exact) for the S2 bound.
// ---------------------------------------------------------------------------
__global__ __launch_bounds__(256) void conv1_i8(
        const float* __restrict__ x,
        const signed char* __restrict__ w1b,   // [2][64 co][64 k]
        const float* __restrict__ bias,
        const double* __restrict__ scr,        // base scr
        const int* __restrict__ amax_x,
        int* __restrict__ amax_out,            // amax1
        signed char* __restrict__ a1q) {
    constexpr int PL = 3472;                   // plane stride bytes
    __shared__ __align__(16) char X[2 * PL];
    __shared__ float redm[4];

    const int b = blockIdx.x;
    const int tid = threadIdx.x;
    const float amx = fmaxf(__int_as_float(*amax_x), 1e-30f);
    const float S = 32512.0f / amx;
    const float S1 = calc_S1(scr, __int_as_float(*amax_x));

    for (int i = tid; i < 2 * PL / 16; i += 256)
        ((int4*)X)[i] = make_int4(0, 0, 0, 0);
    __syncthreads();

    for (int i = tid; i < 768; i += 256) {
        const float4 v = ((const float4*)(x + (long)b * 3072))[i];
        const int e = i * 4;
        const int ci = e >> 10;
        const int rem = e & 1023;
        const int h = rem >> 5, w = rem & 31;
        const int base = ci * 1156 + (h + 1) * 34 + (w + 1);
        const float f[4] = {v.x, v.y, v.z, v.w};
        #pragma unroll
        for (int j = 0; j < 4; j++) {
            const int q = __float2int_rn(f[j] * S);
            const int ql = (q << 24) >> 24;
            const int qh = (q - ql) >> 8;
            X[base + j] = (char)ql;
            X[PL + base + j] = (char)qh;
        }
    }
    __syncthreads();

    const int lane = tid & 63;
    const int wid = tid >> 6;
    const int lm = lane & 15;
    const int kg = lane >> 4;

    const int poff = (kg >= 2) ? PL : 0;
    int cst[16];
    #pragma unroll
    for (int j = 0; j < 16; j++) {
        const int kp = (kg & 1) * 16 + j;
        cst[j] = (kp < 27)
                     ? ((kp / 9) * 1156 + ((kp % 9) / 3) * 34 + (kp % 9) % 3)
                     : 0;
    }

    i32x4 BL[4], BH[4];
    #pragma unroll
    for (int nt = 0; nt < 4; nt++) {
        const int co = nt * 16 + lm;
        BL[nt] = *(const i32x4*)(w1b + (long)co * 64 + kg * 16);
        BH[nt] = *(const i32x4*)(w1b + 4096 + (long)co * 64 + kg * 16);
    }

    const double c2 = scr[2];
    const float alpha = (float)(scr[1] / (c2 > 1.0 ? c2 : 1.0));
    const float dq = alpha / S;
    float tmax = 0.f;
    signed char* yb = a1q + (long)b * 32768;

    for (int tt = 0; tt < 16; ++tt) {
        const int t = wid * 16 + tt;
        const int pp = t * 4 + (lm >> 2);
        const int sub = lm & 3;
        const int h = 2 * (pp >> 4) + (sub >> 1);
        const int w = 2 * (pp & 15) + (sub & 1);
        const int base = poff + h * 34 + w;
        unsigned d[4] = {0u, 0u, 0u, 0u};
        #pragma unroll
        for (int j = 0; j < 16; j++) {
            const unsigned byte = (unsigned char)X[base + cst[j]];
            d[j >> 2] |= byte << ((j & 3) * 8);
        }
        i32x4 Af;
        Af[0] = (int)d[0]; Af[1] = (int)d[1];
        Af[2] = (int)d[2]; Af[3] = (int)d[3];

        const int opp = t * 4 + kg;
        const int ho = opp >> 4, wo = opp & 15;
        signed char* yrow = yb + ((long)ho * 2048) + wo * 64;
        #pragma unroll
        for (int nt = 0; nt < 4; nt++) {
            i32x4 aL = 0, aH = 0;
            aL = __builtin_amdgcn_mfma_i32_16x16x64_i8(Af, BL[nt], aL, 0, 0, 0);
            aH = __builtin_amdgcn_mfma_i32_16x16x64_i8(Af, BH[nt], aH, 0, 0, 0);
            const int s0 = aH[0] * 256 + aL[0];
            const int s1 = aH[1] * 256 + aL[1];
            const int s2 = aH[2] * 256 + aL[2];
            const int s3 = aH[3] * 256 + aL[3];
            int sm = s0 > s1 ? s0 : s1;
            const int sn = s2 > s3 ? s2 : s3;
            sm = sm > sn ? sm : sn;
            const int co = nt * 16 + lm;
            const float o = fmaxf(dq * (float)sm + bias[co], 0.f);
            tmax = fmaxf(tmax, o);
            const int q = (int)(o * S1 + 0.5f);      // o >= 0
            const int ql = (q << 24) >> 24;
            const int qh = (q + 128) >> 8;            // == (q - ql) >> 8
            const int slot = (nt + ((wo + 1) >> 1) + 2 * (ho + 1)) & 3;
            const int off = slot * 16 + lm;           // co & 15 == lm
            yrow[off] = (char)ql;
            yrow[1024 + off] = (char)qh;
        }
    }

    #pragma unroll
    for (int off = 32; off > 0; off >>= 1)
        tmax = fmaxf(tmax, __shfl_down(tmax, off, 64));
    if (lane == 0) redm[wid] = tmax;
    __syncthreads();
    if (tid == 0) {
        float m = fmaxf(fmaxf(redm[0], redm[1]), fmaxf(redm[2], redm[3]));
        atomicMax(amax_out, __float_as_int(m));
    }
}

// ---------------------------------------------------------------------------
// int8 MFMA conv, R22 tiles: MT=4 x NT=4, 128 AGPR acc, 2 blocks/CU.
// MODE 0 (conv2): a1q prequant input, direct-X DMA staging (one barrier),
//   epilogue -> a2q i8 pairs (S2) + amax(a2) atomic.
// MODE 1 (conv3): a2q prequant input, 16 DMAs -> RAW2 + conflict-free b32
//   LDS->LDS swizzle copy; epilogue -> a3q i8 pairs (S3) for fc1.
// ---------------------------------------------------------------------------
template <int CI, int HI, int CO, int HB, int WM, int WN, int MODE, int WIDX>
__global__ __launch_bounds__(256, 2) void conv_i8(
        const signed char* __restrict__ xin,
        const signed char* __restrict__ wp,     // [9][CO][CI] int8 signs
        const float* __restrict__ bias,
        const double* __restrict__ scr,         // base scr
        const int* __restrict__ amax_x,         // amax(x)  (S1)
        const int* __restrict__ amax_1,         // amax(a1) (S2)
        int* __restrict__ amax_2,               // amax(a2) (S3; MODE0 out)
        void* __restrict__ yout) {
    constexpr int CH8 = CI / 64;
    constexpr int NITER = 9 * CH8;
    constexpr int HR = HI / HB;
    constexpr int ROWS = HR + 2;
    constexpr int COLS = HI + 2;
    constexpr int NPIX = ROWS * COLS;
    constexpr int PSTR = NPIX * 64 + 32;    // bytes per g-plane
    constexpr int PO = HI / 2;
    constexpr int POR = HR / 2;
    constexpr int MT = 4, NT = 4;
    constexpr int NPL = 2 * CH8;
    constexpr int RWQ = HI * 64 * 2;        // MODE0 prequant row bytes
    static_assert(WM * WN == 4, "4 waves");
    static_assert(WM * 64 == HR * HI, "M covers slab pixels");
    static_assert(WN * 64 == CO, "N covers all co");
    static_assert(MODE != 0 || (CI == 64 && RWQ == 2048), "conv2 shape");
    static_assert(MODE != 1 || (CI == 128 && HB == 1), "conv3 shape");
    static_assert(HB <= 2, "row compaction assumes <=1 invalid row per end");
    static_assert((COLS & 1) == 0, "swizzle parity uses even COLS");

    __shared__ __align__(16) char X[NPL * PSTR];
    __shared__ __align__(16) char RAW2[(MODE == 1) ? 16384 : 16];
    __shared__ float redm[4];

    const int bimg = blockIdx.x / HB;
    const int hb = blockIdx.x % HB;
    const int tid = threadIdx.x;
    const int lane = tid & 63;
    const int wid = tid >> 6;

    const float S_in = (MODE == 0)
                           ? calc_S1(scr, __int_as_float(*amax_x))
                           : calc_S2(scr, __int_as_float(*amax_1));

    const int rlo = (hb == 0) ? 1 : 0;
    const int rhi = (hb == HB - 1) ? (ROWS - 1) : ROWS;

    if (MODE == 0) {
        // direct-X DMA: interior row = HI*64 = 1024 B per plane
        for (int r = rlo; r < rhi; r++) {
            #pragma unroll
            for (int pl = 0; pl < 2; pl++) {
                if (wid == ((r * 2 + pl) & 3)) {
                    const int h = hb * HR + r - 1;       // in range
                    const signed char* src = xin +
                        (long)(bimg * HI + h) * RWQ + pl * 1024 + lane * 16;
                    GLOAD_LDS16(src, &X[pl * PSTR + (r * COLS + 1) * 64]);
                }
            }
        }
    } else {
        // 16 DMAs -> RAW2 (image chunk is 16 KB contiguous)
        #pragma unroll
        for (int j = 0; j < 16; j++) {
            if (wid == (j & 3)) {
                const signed char* src = xin + (long)bimg * 16384 +
                                         j * 1024 + lane * 16;
                GLOAD_LDS16(src, &RAW2[j * 1024]);
            }
        }
    }

    // halo zero: side cols of all rows + interior of non-DMA'd halo rows.
    // Disjoint from DMA / copy destinations -> race-free.
    {
        const int nfull = ((hb == 0) ? 1 : 0) + ((hb == HB - 1) ? 1 : 0);
        const int NP1 = ROWS * 2;
        const int NPZ = NP1 + nfull * (COLS - 2);
        for (int i = tid; i < NPZ * NPL * 4; i += 256) {
            const int u = i & 3;
            const int t = i >> 2;
            const int g = t % NPL;
            const int e = t / NPL;
            int p;
            if (e < NP1) {
                const int row = e >> 1;
                p = row * COLS + ((e & 1) ? (COLS - 1) : 0);
            } else {
                const int e2 = e - NP1;
                const int inFirst = (hb == 0) && (e2 < COLS - 2);
                const int fr = inFirst ? 0 : (ROWS - 1);
                const int cc = inFirst ? e2
                                       : (e2 - ((hb == 0) ? (COLS - 2) : 0));
                p = fr * COLS + 1 + cc;
            }
            *(int4*)&X[g * PSTR + p * 64 + u * 16] = make_int4(0, 0, 0, 0);
        }
    }

    if (MODE == 1) {
        __syncthreads();    // RAW2 ready (drains DMA)
        // conflict-free b32 LDS->LDS copy RAW2 -> swizzled X interior.
        // dword v: h=v>>9; r=v&511; g=r>>7; byte=(r&127)*4
        #pragma unroll
        for (int k = 0; k < 16; k++) {
            const int v = tid + k * 256;
            const int h = v >> 9;
            const int r = v & 511;
            const int g = r >> 7;
            const int b4 = (r & 127) << 2;
            const unsigned d = *(const unsigned*)&RAW2[v << 2];
            *(unsigned*)&X[g * PSTR + ((h + 1) * COLS + 1) * 64 + b4] = d;
        }
    }
    __syncthreads();

    const int wm = (WM == 1) ? 0 : (wid >> 1);
    const int wn = (WM == 1) ? wid : (wid & 1);
    const int lm = lane & 15;
    const int kg = lane >> 4;

    // pq = (p<<6) | (h&1)<<3 | (w&7)
    int pq[MT];
    #pragma unroll
    for (int mt = 0; mt < MT; mt++) {
        const int m = (wm * MT + mt) * 16 + lm;
        const int pp = m >> 2, sub = m & 3;
        const int lph = pp / PO, lpw = pp % PO;
        const int h = 2 * lph + (sub >> 1);
        const int w = 2 * lpw + (sub & 1);
        pq[mt] = ((h * COLS + w) << 6) | ((h & 1) << 3) | (w & 7);
    }
    const signed char* bp[NT];
    #pragma unroll
    for (int nt = 0; nt < NT; nt++) {
        const int co = (wn * NT + nt) * 16 + lm;
        bp[nt] = wp + (long)co * CI + kg * 16;
    }

    i32x4 accL[MT][NT], accH[MT][NT];
    #pragma unroll
    for (int mt = 0; mt < MT; mt++)
        #pragma unroll
        for (int nt = 0; nt < NT; nt++) { accL[mt][nt] = 0; accH[mt][nt] = 0; }

    i32x4 Bb[2][NT];
    #pragma unroll
    for (int nt = 0; nt < NT; nt++) Bb[0][nt] = *(const i32x4*)(bp[nt]);

    #pragma unroll 2
    for (int it = 0; it < NITER; ++it) {
        const int cur = it & 1, nxt = cur ^ 1;
        if (it + 1 < NITER) {
            const int it1 = it + 1;
            const int tap = it1 / CH8, ch1 = it1 % CH8;
            const int woff = tap * CO * CI + ch1 * 64;
            #pragma unroll
            for (int nt = 0; nt < NT; nt++)
                Bb[nxt][nt] = *(const i32x4*)(bp[nt] + woff);
        }
        const int tap = it / CH8, ch = it % CH8;
        const int ty = tap / 3, tx = tap % 3;       // wave-uniform (SALU)
        const int DT = (ty * COLS + tx) << 6;
        const int typ = ty & 1;
        int ao[MT];
        #pragma unroll
        for (int mt = 0; mt < MT; mt++) {
            const int q = pq[mt];
            const int slot = (kg + ((((q >> 3) & 1) + typ) & 1) * 2 +
                              (((q & 7) + tx) >> 1)) & 3;
            ao[mt] = (q & ~63) + DT + (slot << 4);
        }
        {
            i32x4 Af[MT];
            #pragma unroll
            for (int mt = 0; mt < MT; mt++)
                Af[mt] = *(const i32x4*)&X[ch * PSTR + ao[mt]];
            #pragma unroll
            for (int mt = 0; mt < MT; mt++)
                #pragma unroll
                for (int nt = 0; nt < NT; nt++)
                    accL[mt][nt] = __builtin_amdgcn_mfma_i32_16x16x64_i8(
                        Af[mt], Bb[cur][nt], accL[mt][nt], 0, 0, 0);
        }
        {
            i32x4 Af[MT];
            #pragma unroll
            for (int mt = 0; mt < MT; mt++)
                Af[mt] = *(const i32x4*)&X[(CH8 + ch) * PSTR + ao[mt]];
            #pragma unroll
            for (int mt = 0; mt < MT; mt++)
                #pragma unroll
                for (int nt = 0; nt < NT; nt++)
                    accH[mt][nt] = __builtin_amdgcn_mfma_i32_16x16x64_i8(
                        Af[mt], Bb[cur][nt], accH[mt][nt], 0, 0, 0);
        }
    }

    // epilogue: sum = 256*accH + accL (exact i32); pool in int; dq+bias+relu
    const double* wst = scr + WIDX * 4;
    const double c2 = wst[2];
    const float alpha = (float)(wst[1] / (c2 > 1.0 ? c2 : 1.0));
    const float dq = alpha / S_in;
    if (MODE == 0) {
        // write a2q: [img][h:8][g:4][w*64 + slot*16 + (ci&15)] i8 + amax2
        const float S2 = calc_S2(scr, __int_as_float(*amax_1));
        signed char* oq = (signed char*)yout;
        float tmax = 0.f;
        #pragma unroll
        for (int mt = 0; mt < MT; mt++) {
            const int pp = (wm * MT + mt) * 4 + kg;
            const int lph = pp / PO, lpw = pp % PO;
            const int h = hb * POR + lph;
            const int w = lpw;
            #pragma unroll
            for (int nt = 0; nt < NT; nt++) {
                const int co2 = (wn * NT + nt) * 16 + lm;
                const i32x4 aL = accL[mt][nt], aH = accH[mt][nt];
                int s0 = aH[0] * 256 + aL[0];
                int s1 = aH[1] * 256 + aL[1];
                int s2 = aH[2] * 256 + aL[2];
                int s3 = aH[3] * 256 + aL[3];
                int sm = s0 > s1 ? s0 : s1;
                int sn = s2 > s3 ? s2 : s3;
                sm = sm > sn ? sm : sn;
                const float o = fmaxf(dq * (float)sm + bias[co2], 0.f);
                tmax = fmaxf(tmax, o);
                const int q = (int)(o * S2 + 0.5f);   // o >= 0
                const int ql = (q << 24) >> 24;
                const int qh = (q + 128) >> 8;
                const int slot = (((co2 >> 4) & 3) + ((w + 1) >> 1) +
                                  2 * (h + 1)) & 3;
                const long base = (long)bimg * 16384 + h * 2048 +
                                  (co2 >> 6) * 512 + w * 64 + slot * 16 +
                                  (co2 & 15);
                oq[base] = (char)ql;
                oq[base + 1024] = (char)qh;
            }
        }
        #pragma unroll
        for (int off = 32; off > 0; off >>= 1)
            tmax = fmaxf(tmax, __shfl_down(tmax, off, 64));
        if (lane == 0) redm[wid] = tmax;
        __syncthreads();
        if (tid == 0) {
            float m = fmaxf(fmaxf(redm[0], redm[1]), fmaxf(redm[2], redm[3]));
            atomicMax(amax_2, __float_as_int(m));
        }
    } else {
        // write a3q: [img][px:16][lo 256 | hi 256] i8 (fc1 layout)
        const float S3 = calc_S3(scr, __int_as_float(*amax_2));
        signed char* oq = (signed char*)yout;
        #pragma unroll
        for (int mt = 0; mt < MT; mt++) {
            const int pp = (wm * MT + mt) * 4 + kg;
            const int lph = pp / PO, lpw = pp % PO;
            const int gpp = (hb * POR + lph) * PO + lpw;
            signed char* yr = oq + (long)bimg * 8192 + gpp * 512;
            #pragma unroll
            for (int nt = 0; nt < NT; nt++) {
                const int co = (wn * NT + nt) * 16 + lm;
                const i32x4 aL = accL[mt][nt], aH = accH[mt][nt];
                int s0 = aH[0] * 256 + aL[0];
                int s1 = aH[1] * 256 + aL[1];
                int s2 = aH[2] * 256 + aL[2];
                int s3 = aH[3] * 256 + aL[3];
                int sm = s0 > s1 ? s0 : s1;
                int sn = s2 > s3 ? s2 : s3;
                sm = sm > sn ? sm : sn;
                const float o = fmaxf(dq * (float)sm + bias[co], 0.f);
                const int q = (int)(o * S3 + 0.5f);   // o >= 0
                const int ql = (q << 24) >> 24;
                const int qh = (q + 128) >> 8;
                yr[co] = (char)ql;          // lo plane at +0
                yr[256 + co] = (char)qh;    // hi plane at +256
            }
        }
    }
}

// ---------------------------------------------------------------------------
// fc1 i8 MFMA: 128x128 tiles, K'=4096 (px*256+c), lo/hi planes, split-K S.
// Grid (8, 2, S). Pure integer; parts stores float(256*accH + accL)
// (exact: |part| < 2^23). a3q per-pixel layout [lo 256 | hi 256].
// ---------------------------------------------------------------------------
template <int S>
__global__ __launch_bounds__(256) void fc1_i8(
        const signed char* __restrict__ A,    // a3q [1024][16px][lo|hi] 8192B
        const signed char* __restrict__ Bw,   // wtf1b8 [256][4096] i8
        float* __restrict__ parts) {
    constexpr int KCH = 4096 / S;
    constexpr int NCH = KCH / 64;
    const int m0 = blockIdx.x * 128;
    const int n0 = blockIdx.y * 128;
    const int s = blockIdx.z;
    const int tid = threadIdx.x;
    const int lane = tid & 63, wid = tid >> 6;
    const int wm = wid >> 1, wn = wid & 1;
    const int lm = lane & 15, kg = lane >> 4;

    const int k0 = s * KCH;
    const signed char* ap[4];
    const signed char* bp[4];
    #pragma unroll
    for (int t = 0; t < 4; t++) {
        ap[t] = A + (long)(m0 + wm * 64 + t * 16 + lm) * 8192;
        bp[t] = Bw + (long)(n0 + wn * 64 + t * 16 + lm) * 4096 + k0 + kg * 16;
    }

    i32x4 accL[4][4], accH[4][4];
    #pragma unroll
    for (int mt = 0; mt < 4; mt++)
        #pragma unroll
        for (int nt = 0; nt < 4; nt++) { accL[mt][nt] = 0; accH[mt][nt] = 0; }

    #pragma unroll
    for (int ch = 0; ch < NCH; ++ch) {
        const int kb = k0 + ch * 64;
        const int aoff = (kb >> 8) * 512 + (kb & 255) + kg * 16;
        i32x4 Ah[4], Al[4], Bb[4];
        #pragma unroll
        for (int t = 0; t < 4; t++) {
            Al[t] = *(const i32x4*)(ap[t] + aoff);          // lo plane (+0)
            Ah[t] = *(const i32x4*)(ap[t] + aoff + 256);    // hi plane (+256)
            Bb[t] = *(const i32x4*)(bp[t] + ch * 64);
        }
        #pragma unroll
        for (int mt = 0; mt < 4; mt++)
            #pragma unroll
            for (int nt = 0; nt < 4; nt++) {
                accH[mt][nt] = __builtin_amdgcn_mfma_i32_16x16x64_i8(
                    Ah[mt], Bb[nt], accH[mt][nt], 0, 0, 0);
                accL[mt][nt] = __builtin_amdgcn_mfma_i32_16x16x64_i8(
                    Al[mt], Bb[nt], accL[mt][nt], 0, 0, 0);
            }
    }

    #pragma unroll
    for (int mt = 0; mt < 4; mt++) {
        #pragma unroll
        for (int r = 0; r < 4; r++) {
            const int b = m0 + wm * 64 + mt * 16 + kg * 4 + r;
            #pragma unroll
            for (int nt = 0; nt < 4; nt++) {
                const int j = n0 + wn * 64 + nt * 16 + lm;
                const int sum = accH[mt][nt][r] * 256 + accL[mt][nt][r];
                parts[((long)s * 1024 + b) * 256 + j] = (float)sum;
            }
        }
    }
}

// ---------------------------------------------------------------------------
// Fused fc1-reduce + fc2. fc1 sums are S3-scaled integers: h = alpha*s/S3.
// fc2 weights are i8 signs; alpha4 applied once at the end.
// ---------------------------------------------------------------------------
template <int S>
__global__ __launch_bounds__(256) void fc2_fused(
        const float* __restrict__ parts,
        const double* __restrict__ scr,      // base scr
        const int* __restrict__ amax_2,      // amax(a2) for S3
        const float* __restrict__ bf1v,
        const signed char* __restrict__ wtf2b8,
        const float* __restrict__ bf2v,
        float* __restrict__ out) {
    __shared__ float sf[256];
    const int b = blockIdx.x;
    const int j = threadIdx.x;
    float s = 0.f;
    #pragma unroll
    for (int p = 0; p < S; p++)
        s += parts[(long)p * 262144 + (long)b * 256 + j];
    const double c2 = scr[14];
    const float alpha = (float)(scr[13] / (c2 > 1.0 ? c2 : 1.0));
    const float S3 = calc_S3(scr, __int_as_float(*amax_2));
    sf[j] = fmaxf(alpha * s / S3 + bf1v[j], 0.f);
    __syncthreads();
    const double c4 = scr[18];
    const float alpha4 = (float)(scr[17] / (c4 > 1.0 ? c4 : 1.0));
    const int lane = threadIdx.x & 63, wid = threadIdx.x >> 6;
    for (int k = wid; k < 10; k += 4) {
        const signed char* wr = wtf2b8 + k * 256;
        float acc = 0.f;
        #pragma unroll
        for (int t = 0; t < 4; t++)
            acc += sf[lane + t * 64] * (float)wr[lane + t * 64];
        #pragma unroll
        for (int off = 32; off > 0; off >>= 1)
            acc += __shfl_down(acc, off, 64);
        if (lane == 0) out[(long)b * 10 + k] = acc * alpha4 + bf2v[k];
    }
}

extern "C" void kernel_launch(void* const* d_in, const int* in_sizes, int n_in,
                              void* d_out, int out_size, void* d_ws, size_t ws_size,
                              hipStream_t stream) {
    const float* x   = (const float*)d_in[0];
    const float* w1  = (const float*)d_in[1];
    const float* b1  = (const float*)d_in[2];
    const float* w2  = (const float*)d_in[3];
    const float* b2  = (const float*)d_in[4];
    const float* w3  = (const float*)d_in[5];
    const float* b3  = (const float*)d_in[6];
    const float* wf1 = (const float*)d_in[7];
    const float* bf1 = (const float*)d_in[8];
    const float* wf2 = (const float*)d_in[9];
    const float* bf2 = (const float*)d_in[10];
    float* out = (float*)d_out;
    float* ws = (float*)d_ws;

    const int B = 1024;

    signed char*    w1b    = (signed char*)(ws + WS_W1B);
    signed char*    w2p8   = (signed char*)(ws + WS_W2P);
    signed char*    w3p8   = (signed char*)(ws + WS_W3P);
    signed char*    wtf1b8 = (signed char*)(ws + WS_WTF1);
    signed char*    wtf2b8 = (signed char*)(ws + WS_WTF2);
    signed char*    a1q    = (signed char*)(ws + WS_A1);
    signed char*    a2q    = (signed char*)(ws + WS_A2);
    signed char*    a3q    = (signed char*)(ws + WS_A3);
    double*         scr    = (double*)(ws + WS_SCR);
    int*            iscr   = (int*)(scr + 20);
    int*            amaxx  = iscr;          // amax(x)
    int*            amax1  = iscr + 1;      // amax(a1)
    int*            amax2  = iscr + 2;      // amax(a2)
    float*          parts  = ws + WS_A1;    // alias: a1q dead after conv2

    hipMemsetAsync(scr, 0, 26 * sizeof(double), stream);

    TernArgs ta;
    ta.w[0] = w1;  ta.n[0] = 64 * 27;
    ta.w[1] = w2;  ta.n[1] = 128 * 64 * 9;
    ta.w[2] = w3;  ta.n[2] = 256 * 128 * 9;
    ta.w[3] = wf1; ta.n[3] = 256 * 4096;
    ta.w[4] = wf2; ta.n[4] = 10 * 256;
    ta.w[5] = x;   ta.n[5] = 1024 * 3 * 32 * 32;   // amax(x)

    hipLaunchKernelGGL(tern_stats1, dim3(128, 6), dim3(256), 0, stream, ta, scr);
    hipLaunchKernelGGL(tern_stats2, dim3(128, 6), dim3(256), 0, stream,
                       ta, b1, b2, b3, w1b, w2p8, w3p8, wtf1b8, wtf2b8, scr);

    // conv1: i8 MFMA -> prequantized a1q + amax1
    hipLaunchKernelGGL(conv1_i8, dim3(B), dim3(256), 0, stream,
                       x, w1b, b1, scr, amaxx, amax1, a1q);

    // conv2: CI=64, HI=16, CO=128, HB=2 -> 2048 blocks; a2q out + amax2
    hipLaunchKernelGGL((conv_i8<64, 16, 128, 2, 2, 2, 0, 1>), dim3(B * 2),
                       dim3(256), 0, stream, a1q, w2p8, b2, scr, amaxx,
                       amax1, amax2, a2q);

    // conv3: CI=128, HI=8, CO=256, HB=1 -> 1024 blocks; a3q i8 out (S3)
    hipLaunchKernelGGL((conv_i8<128, 8, 256, 1, 1, 4, 1, 2>), dim3(B),
                       dim3(256), 0, stream, a2q, w3p8, b3, scr, amaxx,
                       amax1, amax2, a3q);

    // fc1: i8 MFMA 128x128 tiles, split-K (S=16 -> 256 blocks)
    hipLaunchKernelGGL((fc1_i8<FC1_S>), dim3(8, 2, FC1_S), dim3(256), 0, stream,
                       a3q, wtf1b8, parts);

    // fused fc1-reduce + fc2 (integer sums, /S3; alpha4 at the end)
    hipLaunchKernelGGL((fc2_fused<FC1_S>), dim3(B), dim3(256), 0, stream,
                       parts, scr, amax2, bf1, wtf2b8, bf2, out);
}